// Round 4
// baseline (241.307 us; speedup 1.0000x reference)
//
#include <hip/hip_runtime.h>

// ALiBi bias subtraction: out[b,h,i,j] = scores[b,h,i,j] - slope(h)*(i-j)
// (offset cancels in pos_diff). B=2, H=16, S=2048 -> shift/mask index decomp.
// Streaming, memory-bound. v4: A/B isolation — keep 4x MLP unroll from v3,
// REMOVE nontemporal hints (plain loads/stores, same as the 6.3 TB/s copy
// ubench). Round-3 regression (218->241) suspected to be the NT cache-bypass.

typedef float f32x4 __attribute__((ext_vector_type(4)));

__device__ __forceinline__ f32x4 alibi_apply(f32x4 s, unsigned int idx4) {
    const unsigned int e = idx4 << 2;              // element index of lane's .x
    const int j = (int)(e & 2047u);                // S = 2048
    const int i = (int)((e >> 11) & 2047u);
    const int h = (int)((e >> 22) & 15u);          // H = 16
    const float slope = exp2f(-0.5f * (float)(h + 1));  // 2^(-8*(h+1)/16)
    const int d = i - j;
    f32x4 o;
    o.x = s.x - slope * (float)(d);
    o.y = s.y - slope * (float)(d - 1);
    o.z = s.z - slope * (float)(d - 2);
    o.w = s.w - slope * (float)(d - 3);
    return o;
}

__global__ __launch_bounds__(256) void alibi_kernel(const f32x4* __restrict__ in,
                                                    f32x4* __restrict__ out,
                                                    unsigned int n4) {
    const unsigned int stride = gridDim.x * blockDim.x;
    unsigned int idx = blockIdx.x * blockDim.x + threadIdx.x;

    // Main loop: 4 independent loads in flight before any compute/store.
    for (; idx + 3u * stride < n4; idx += 4u * stride) {
        const unsigned int i0 = idx;
        const unsigned int i1 = idx + stride;
        const unsigned int i2 = idx + 2u * stride;
        const unsigned int i3 = idx + 3u * stride;
        f32x4 s0 = in[i0];
        f32x4 s1 = in[i1];
        f32x4 s2 = in[i2];
        f32x4 s3 = in[i3];
        f32x4 o0 = alibi_apply(s0, i0);
        f32x4 o1 = alibi_apply(s1, i1);
        f32x4 o2 = alibi_apply(s2, i2);
        f32x4 o3 = alibi_apply(s3, i3);
        out[i0] = o0;
        out[i1] = o1;
        out[i2] = o2;
        out[i3] = o3;
    }
    // Tail (never taken for the bench shape: n4 % (4*stride) == 0).
    for (; idx < n4; idx += stride) {
        out[idx] = alibi_apply(in[idx], idx);
    }
}

extern "C" void kernel_launch(void* const* d_in, const int* in_sizes, int n_in,
                              void* d_out, int out_size, void* d_ws, size_t ws_size,
                              hipStream_t stream) {
    const f32x4* in = (const f32x4*)d_in[0];
    f32x4* out = (f32x4*)d_out;
    const unsigned int n4 = (unsigned int)(out_size / 4);  // 33554432 float4s
    const int block = 256;
    const int grid = 2048;  // 8 blocks/CU * 256 CUs; 64 iters/thread -> 16 unrolled
    alibi_kernel<<<grid, block, 0, stream>>>(in, out, n4);
}

// Round 5
// 197.695 us; speedup vs baseline: 1.2206x; 1.2206x over previous
//
#include <hip/hip_runtime.h>

// ALiBi bias subtraction: out[b,h,i,j] = scores[b,h,i,j] - slope(h)*(i-j)
// (offset cancels in pos_diff). B=2, H=16, S=2048 -> shift/mask index decomp.
// v5: 4x MLP unroll with CONTIGUOUS chunks. r3/r4 showed the 8-MiB-strided
// unroll regressed (channel aliasing: 2^23-apart addrs -> same HBM channel).
// Now each block handles a contiguous 16 KiB chunk/iter: 4 loads 4 KiB apart
// (adjacent channels), blocks grid-stride over chunks.

typedef float f32x4 __attribute__((ext_vector_type(4)));

__device__ __forceinline__ f32x4 alibi_apply(f32x4 s, unsigned int idx4) {
    const unsigned int e = idx4 << 2;              // element index of lane's .x
    const int j = (int)(e & 2047u);                // S = 2048
    const int i = (int)((e >> 11) & 2047u);
    const int h = (int)((e >> 22) & 15u);          // H = 16
    const float slope = exp2f(-0.5f * (float)(h + 1));  // 2^(-8*(h+1)/16)
    const int d = i - j;
    f32x4 o;
    o.x = s.x - slope * (float)(d);
    o.y = s.y - slope * (float)(d - 1);
    o.z = s.z - slope * (float)(d - 2);
    o.w = s.w - slope * (float)(d - 3);
    return o;
}

__global__ __launch_bounds__(256) void alibi_kernel(const f32x4* __restrict__ in,
                                                    f32x4* __restrict__ out,
                                                    unsigned int n4) {
    // Each block-iteration: contiguous chunk of 4*256 float4s (16 KiB).
    const unsigned int chunk_elems = 4u * 256u;                 // 1024 float4s
    const unsigned int nchunks = n4 / chunk_elems;              // 32768 (exact)
    const unsigned int t = threadIdx.x;

    for (unsigned int c = blockIdx.x; c < nchunks; c += gridDim.x) {
        const unsigned int base = c * chunk_elems;
        const unsigned int i0 = base + t;
        const unsigned int i1 = base + 256u + t;
        const unsigned int i2 = base + 512u + t;
        const unsigned int i3 = base + 768u + t;
        f32x4 s0 = in[i0];
        f32x4 s1 = in[i1];
        f32x4 s2 = in[i2];
        f32x4 s3 = in[i3];
        f32x4 o0 = alibi_apply(s0, i0);
        f32x4 o1 = alibi_apply(s1, i1);
        f32x4 o2 = alibi_apply(s2, i2);
        f32x4 o3 = alibi_apply(s3, i3);
        out[i0] = o0;
        out[i1] = o1;
        out[i2] = o2;
        out[i3] = o3;
    }
    // Tail for non-multiple sizes (never taken for the bench shape).
    const unsigned int tail_start = (n4 / chunk_elems) * chunk_elems;
    for (unsigned int idx = tail_start + blockIdx.x * blockDim.x + t; idx < n4;
         idx += gridDim.x * blockDim.x) {
        out[idx] = alibi_apply(in[idx], idx);
    }
}

extern "C" void kernel_launch(void* const* d_in, const int* in_sizes, int n_in,
                              void* d_out, int out_size, void* d_ws, size_t ws_size,
                              hipStream_t stream) {
    const f32x4* in = (const f32x4*)d_in[0];
    f32x4* out = (f32x4*)d_out;
    const unsigned int n4 = (unsigned int)(out_size / 4);  // 33554432 float4s
    const int block = 256;
    const int grid = 2048;  // 8 blocks/CU * 256 CUs; 16 chunk-iters per block
    alibi_kernel<<<grid, block, 0, stream>>>(in, out, n4);
}